// Round 5
// baseline (323.931 us; speedup 1.0000x reference)
//
#include <hip/hip_runtime.h>
#include <hip/hip_fp16.h>

#define NUSERS 100000
#define NITEMS 50000
#define NTOT   150000   // NUSERS + NITEMS
#define DIM    64
#define NNZ    2000000
#define NLAYERS 3
#define NB     293      // buckets of 512 rows: 293*512 = 150016 >= NTOT
#define BSH    9        // bucket shift (512 rows)
#define BMSK   511
#define CHUNK  4096     // edges per partition block

// ---------------------------------------------------------------------------
// non-temporal helpers (keep single-use streams out of L2 so the gather
// table stays resident)
// ---------------------------------------------------------------------------
typedef unsigned int v4u __attribute__((ext_vector_type(4)));
typedef unsigned int v2u __attribute__((ext_vector_type(2)));

__device__ __forceinline__ uint4 nt_load_u4(const void* p) {
    v4u v = __builtin_nontemporal_load((const v4u*)p);
    union { v4u v; uint4 u; } c; c.v = v; return c.u;
}
__device__ __forceinline__ void nt_store_u4(void* p, uint4 u) {
    union { uint4 u; v4u v; } c; c.u = u;
    __builtin_nontemporal_store(c.v, (v4u*)p);
}
__device__ __forceinline__ void nt_store_u2(void* p, uint2 u) {
    union { uint2 u; v2u v; } c; c.u = u;
    __builtin_nontemporal_store(c.v, (v2u*)p);
}
__device__ __forceinline__ long long nt_load_ll(const void* p) {
    return __builtin_nontemporal_load((const long long*)p);
}

// ---------------------------------------------------------------------------
// block-wide inclusive scan, 512 threads: per-wave shfl scan + 8-entry
// cross-wave scan. Caller barriers before (data ready) are its responsibility.
// ---------------------------------------------------------------------------
__device__ __forceinline__ int block_incl_scan512(int own, int* wsum, int t) {
    int incl = own;
    #pragma unroll
    for (int o = 1; o < 64; o <<= 1) {
        int v = __shfl_up(incl, o, 64);
        if ((t & 63) >= o) incl += v;
    }
    if ((t & 63) == 63) wsum[t >> 6] = incl;
    __syncthreads();
    if (t < 8) {
        int v = wsum[t];
        #pragma unroll
        for (int o = 1; o < 8; o <<= 1) {
            int u = __shfl_up(v, o, 64);
            if (t >= o) v += u;
        }
        wsum[t] = v;
    }
    __syncthreads();
    if (t >= 64) incl += wsum[(t >> 6) - 1];
    return incl;
}

// ---------------------------------------------------------------------------
// init: b0 = fp16(concat(user_emb, item_emb))
// ---------------------------------------------------------------------------
__global__ void lg_inith(const float* __restrict__ ue, const float* __restrict__ ie,
                         __half* __restrict__ b0) {
    const int total4 = NTOT * DIM / 4;
    const int ubound4 = NUSERS * DIM / 4;
    const float4* ue4 = (const float4*)ue;
    const float4* ie4 = (const float4*)ie;
    uint2* out = (uint2*)b0;
    for (int i = blockIdx.x * blockDim.x + threadIdx.x; i < total4;
         i += gridDim.x * blockDim.x) {
        const float4 v = (i < ubound4) ? ue4[i] : ie4[i - ubound4];
        __half2 h0 = __floats2half2_rn(v.x, v.y);
        __half2 h1 = __floats2half2_rn(v.z, v.w);
        uint2 u;
        u.x = *(const unsigned int*)&h0;
        u.y = *(const unsigned int*)&h1;
        nt_store_u2(&out[i], u);
    }
}

// ---------------------------------------------------------------------------
// bucket histogram: bucket = row >> 9. LDS hist, one global atomic/(blk,bkt).
// ---------------------------------------------------------------------------
__global__ void lg_bhist(const int* __restrict__ row, int* __restrict__ bcnt) {
    __shared__ int h[NB];
    for (int i = threadIdx.x; i < NB; i += blockDim.x) h[i] = 0;
    __syncthreads();
    for (int e = blockIdx.x * blockDim.x + threadIdx.x; e < NNZ;
         e += gridDim.x * blockDim.x)
        atomicAdd(&h[row[e] >> BSH], 1);
    __syncthreads();
    for (int i = threadIdx.x; i < NB; i += blockDim.x)
        if (h[i]) atomicAdd(&bcnt[i], h[i]);
}

// ---------------------------------------------------------------------------
// bucket scan: bptr[0..NB] exclusive ptr, bcur = segment cursor base
// ---------------------------------------------------------------------------
__global__ __launch_bounds__(512) void lg_bscan(const int* __restrict__ bcnt,
                                                int* __restrict__ bptr,
                                                int* __restrict__ bcur) {
    __shared__ int wsum[8];
    const int t = threadIdx.x;
    const int own = (t < NB) ? bcnt[t] : 0;
    const int incl = block_incl_scan512(own, wsum, t);
    if (t < NB) {
        bptr[t + 1] = incl;
        bcur[t] = incl - own;
    }
    if (t == 0) bptr[0] = 0;
}

// ---------------------------------------------------------------------------
// partition: chunk-aggregated scatter into bucket segments. LDS-stage CHUNK
// edges grouped by bucket, claim each bucket run with ONE global atomic,
// flush coalesced. tmp entry: ((row&511)<<18 | col, val_f32).
// ---------------------------------------------------------------------------
__global__ __launch_bounds__(512) void lg_part(const int* __restrict__ row,
                                               const int* __restrict__ col,
                                               const float* __restrict__ vals,
                                               int* __restrict__ bcur,
                                               int2* __restrict__ tmp) {
    __shared__ int h[NB], off[NB], cnt2[NB], bs[NB];
    __shared__ int wsum[8];
    __shared__ unsigned short bk[CHUNK];
    __shared__ int2 stag[CHUNK];
    const int t = threadIdx.x;
    const int e0 = blockIdx.x * CHUNK;
    const int n = (NNZ - e0 < CHUNK) ? (NNZ - e0) : CHUNK;

    for (int i = t; i < NB; i += 512) { h[i] = 0; cnt2[i] = 0; }
    __syncthreads();
    for (int i = t; i < n; i += 512)
        atomicAdd(&h[row[e0 + i] >> BSH], 1);
    __syncthreads();
    const int own = (t < NB) ? h[t] : 0;
    const int incl = block_incl_scan512(own, wsum, t);
    if (t < NB) off[t] = incl - own;
    __syncthreads();
    for (int i = t; i < n; i += 512) {
        const int e = e0 + i;
        const int r = row[e];
        const int b = r >> BSH;
        const int k = atomicAdd(&cnt2[b], 1);
        const int s = off[b] + k;
        stag[s] = make_int2(((r & BMSK) << 18) | col[e], __float_as_int(vals[e]));
        bk[s] = (unsigned short)b;
    }
    __syncthreads();
    if (t < NB && own > 0) bs[t] = atomicAdd(&bcur[t], own);
    __syncthreads();
    for (int s = t; s < n; s += 512) {
        const int b = bk[s];
        const int2 v = stag[s];
        nt_store_u2(&tmp[bs[b] + (s - off[b])],
                    make_uint2((unsigned)v.x, (unsigned)v.y));
    }
}

// ---------------------------------------------------------------------------
// rowsort: one block per 512-row bucket. LDS row-hist + two-level scan ->
// per-row [beg,end) in be[]; scatter (col,val) into the bucket's contiguous
// (L2-resident, ~55 KB) cedge region.
// ---------------------------------------------------------------------------
__global__ __launch_bounds__(512) void lg_rsort(const int2* __restrict__ tmp,
                                                const int* __restrict__ bptr,
                                                int2* __restrict__ be,
                                                int2* __restrict__ cedge) {
    __shared__ int h[512];
    __shared__ int wsum[8];
    const int b = blockIdx.x;
    const int t = threadIdx.x;
    const int s0 = bptr[b], s1 = bptr[b + 1];
    h[t] = 0;
    __syncthreads();
    for (int s = s0 + t; s < s1; s += 512)
        atomicAdd(&h[(tmp[s].x >> 18) & BMSK], 1);
    __syncthreads();
    const int own = h[t];
    const int incl = block_incl_scan512(own, wsum, t);
    const int excl = incl - own;
    const int r = (b << BSH) + t;
    if (r < NTOT) be[r] = make_int2(s0 + excl, s0 + excl + own);
    __syncthreads();
    h[t] = excl;                        // reuse as per-row cursor
    __syncthreads();
    for (int s = s0 + t; s < s1; s += 512) {
        const int2 ev = tmp[s];
        const int rl = (ev.x >> 18) & BMSK;
        const int k = atomicAdd(&h[rl], 1);
        nt_store_u2(&cedge[s0 + k],
                    make_uint2((unsigned)(ev.x & 0x3FFFF), (unsigned)ev.y));
    }
}

// ---------------------------------------------------------------------------
// gather core: wave = one row. 8 groups x 8 lanes; 2-deep software pipeline
// (prefetch next cedge entry + table row before consuming current).
// cedge reads are non-temporal (single-use stream); table reads cached.
// ---------------------------------------------------------------------------
__device__ __forceinline__ void row_gather8(const int2* __restrict__ be,
                                            const int2* __restrict__ cedge,
                                            const __half* __restrict__ cur,
                                            int r, int lane, float sum[8]) {
    const int2 p = be[r];
    const int g = lane >> 3;
    const int d = lane & 7;
    #pragma unroll
    for (int k = 0; k < 8; ++k) sum[k] = 0.0f;
    int e = p.x + g;
    if (e < p.y) {
        long long raw = nt_load_ll(&cedge[e]);
        uint4 q = ((const uint4*)(cur + ((size_t)(int)raw << 6)))[d];
        for (e += 8; e < p.y; e += 8) {
            const long long raw2 = nt_load_ll(&cedge[e]);
            const uint4 q2 = ((const uint4*)(cur + ((size_t)(int)raw2 << 6)))[d];
            const float v = __int_as_float((int)(raw >> 32));
            const __half2* hp = (const __half2*)&q;
            #pragma unroll
            for (int k = 0; k < 4; ++k) {
                const float2 f = __half22float2(hp[k]);
                sum[2 * k]     += v * f.x;
                sum[2 * k + 1] += v * f.y;
            }
            raw = raw2; q = q2;
        }
        const float v = __int_as_float((int)(raw >> 32));
        const __half2* hp = (const __half2*)&q;
        #pragma unroll
        for (int k = 0; k < 4; ++k) {
            const float2 f = __half22float2(hp[k]);
            sum[2 * k]     += v * f.x;
            sum[2 * k + 1] += v * f.y;
        }
    }
    #pragma unroll
    for (int m = 8; m < 64; m <<= 1) {
        #pragma unroll
        for (int k = 0; k < 8; ++k)
            sum[k] += __shfl_xor(sum[k], m, 64);
    }
}

// mid layer: nxt = fp16(A * cur)
__global__ void lg_gmid(const int2* __restrict__ be, const int2* __restrict__ cedge,
                        const __half* __restrict__ cur, __half* __restrict__ nxt) {
    const int gid = blockIdx.x * blockDim.x + threadIdx.x;
    const int r = gid >> 6, lane = gid & 63;
    if (r >= NTOT) return;
    float s[8];
    row_gather8(be, cedge, cur, r, lane, s);
    if ((lane >> 3) == 0) {
        __half2 o[4];
        #pragma unroll
        for (int k = 0; k < 4; ++k) o[k] = __floats2half2_rn(s[2 * k], s[2 * k + 1]);
        nt_store_u4((uint4*)(nxt + ((size_t)r << 6)) + (lane & 7), *(const uint4*)o);
    }
}

// last layer, fused: acc = 0.25*(b0 + b1 + b2 + A*b2)   (fp32 output)
__global__ void lg_glast(const int2* __restrict__ be, const int2* __restrict__ cedge,
                         const __half* __restrict__ b0, const __half* __restrict__ b1,
                         const __half* __restrict__ b2, float* __restrict__ acc) {
    const int gid = blockIdx.x * blockDim.x + threadIdx.x;
    const int r = gid >> 6, lane = gid & 63;
    if (r >= NTOT) return;
    float s[8];
    row_gather8(be, cedge, b2, r, lane, s);
    if ((lane >> 3) == 0) {
        const int d = lane & 7;
        const size_t base = (size_t)r << 6;
        const uint4 q0 = nt_load_u4((const uint4*)(b0 + base) + d);
        const uint4 q1 = nt_load_u4((const uint4*)(b1 + base) + d);
        const uint4 q2 = nt_load_u4((const uint4*)(b2 + base) + d);
        const __half2* h0 = (const __half2*)&q0;
        const __half2* h1 = (const __half2*)&q1;
        const __half2* h2 = (const __half2*)&q2;
        float out[8];
        #pragma unroll
        for (int k = 0; k < 4; ++k) {
            const float2 f0 = __half22float2(h0[k]);
            const float2 f1 = __half22float2(h1[k]);
            const float2 f2 = __half22float2(h2[k]);
            out[2 * k]     = 0.25f * (f0.x + f1.x + f2.x + s[2 * k]);
            out[2 * k + 1] = 0.25f * (f0.y + f1.y + f2.y + s[2 * k + 1]);
        }
        float* dst = acc + base + (size_t)d * 8;
        nt_store_u4(dst,     *(const uint4*)&out[0]);
        nt_store_u4(dst + 4, *(const uint4*)&out[4]);
    }
}

// ---------------------------------------------------------------------------
// Fallback (round-1) kernels: edge-parallel scatter with fp32 atomics
// ---------------------------------------------------------------------------
__global__ void lg_init2(const float* __restrict__ ue, const float* __restrict__ ie,
                         float* __restrict__ cur, float* __restrict__ acc) {
    const int total4 = NTOT * DIM / 4;
    const int ubound4 = NUSERS * DIM / 4;
    const float4* ue4 = (const float4*)ue;
    const float4* ie4 = (const float4*)ie;
    float4* cur4 = (float4*)cur;
    float4* acc4 = (float4*)acc;
    for (int i = blockIdx.x * blockDim.x + threadIdx.x; i < total4;
         i += gridDim.x * blockDim.x) {
        float4 v = (i < ubound4) ? ue4[i] : ie4[i - ubound4];
        cur4[i] = v;
        float4 a;
        a.x = 0.25f * v.x; a.y = 0.25f * v.y; a.z = 0.25f * v.z; a.w = 0.25f * v.w;
        acc4[i] = a;
    }
}

__global__ void lg_scatter(const float* __restrict__ cur, const float* __restrict__ vals,
                           const int* __restrict__ row, const int* __restrict__ col,
                           float* __restrict__ next) {
    const long long total = (long long)NNZ * 64;
    for (long long t = blockIdx.x * (long long)blockDim.x + threadIdx.x; t < total;
         t += (long long)gridDim.x * blockDim.x) {
        const int e    = (int)(t >> 6);
        const int lane = (int)(t & 63);
        const float m  = cur[(long long)col[e] * DIM + lane] * vals[e];
        atomicAdd(&next[(long long)row[e] * DIM + lane], m);
    }
}

__global__ void lg_axpy(const float* __restrict__ next, float* __restrict__ acc) {
    const int total4 = NTOT * DIM / 4;
    const float4* n4 = (const float4*)next;
    float4* a4 = (float4*)acc;
    for (int i = blockIdx.x * blockDim.x + threadIdx.x; i < total4;
         i += gridDim.x * blockDim.x) {
        float4 n = n4[i];
        float4 a = a4[i];
        a.x += 0.25f * n.x; a.y += 0.25f * n.y; a.z += 0.25f * n.z; a.w += 0.25f * n.w;
        a4[i] = a;
    }
}

extern "C" void kernel_launch(void* const* d_in, const int* in_sizes, int n_in,
                              void* d_out, int out_size, void* d_ws, size_t ws_size,
                              hipStream_t stream) {
    const float* ue   = (const float*)d_in[0];
    const float* ie   = (const float*)d_in[1];
    const float* vals = (const float*)d_in[2];
    const int*   row  = (const int*)d_in[3];
    const int*   col  = (const int*)d_in[4];

    float* acc = (float*)d_out;

    const size_t EMB = (size_t)NTOT * DIM;       // 9.6M elements

    // workspace layout (fp16 path)
    __half* b0   = (__half*)d_ws;                // 19.2 MB
    __half* b1   = b0 + EMB;                     // 19.2 MB
    __half* b2   = b1 + EMB;                     // 19.2 MB
    int2* tmp    = (int2*)(b2 + EMB);            // 16 MB  (bucket-partitioned)
    int2* cedge  = tmp + NNZ;                    // 16 MB  (row-sorted (col,val))
    int2* be     = cedge + NNZ;                  // 1.2 MB (per-row [beg,end))
    int*  bcnt   = (int*)(be + NTOT);            // NB
    int*  bptr   = bcnt + NB;                    // NB+1
    int*  bcur   = bptr + NB + 1;                // NB
    const size_t need = (size_t)((char*)(bcur + NB) - (char*)d_ws);   // ~90.8 MB

    if (ws_size >= need) {
        const int nchunks = (NNZ + CHUNK - 1) / CHUNK;   // 489
        const int gblocks = (NTOT * DIM) / 256;          // 37500

        lg_inith<<<1024, 256, 0, stream>>>(ue, ie, b0);
        hipMemsetAsync(bcnt, 0, NB * sizeof(int), stream);
        lg_bhist<<<256, 256, 0, stream>>>(row, bcnt);
        lg_bscan<<<1, 512, 0, stream>>>(bcnt, bptr, bcur);
        lg_part<<<nchunks, 512, 0, stream>>>(row, col, vals, bcur, tmp);
        lg_rsort<<<NB, 512, 0, stream>>>(tmp, bptr, be, cedge);

        lg_gmid <<<gblocks, 256, 0, stream>>>(be, cedge, b0, b1);
        lg_gmid <<<gblocks, 256, 0, stream>>>(be, cedge, b1, b2);
        lg_glast<<<gblocks, 256, 0, stream>>>(be, cedge, b0, b1, b2, acc);
    } else {
        // minimal fallback: round-1 scatter path (2 x 38.4 MB fp32)
        float* cur = (float*)d_ws;
        float* nxt = cur + EMB;
        const size_t buf_bytes = EMB * sizeof(float);
        lg_init2<<<1024, 256, 0, stream>>>(ue, ie, cur, acc);
        for (int l = 0; l < NLAYERS; ++l) {
            hipMemsetAsync(nxt, 0, buf_bytes, stream);
            lg_scatter<<<8192, 256, 0, stream>>>(cur, vals, row, col, nxt);
            lg_axpy<<<1024, 256, 0, stream>>>(nxt, acc);
            float* t = cur; cur = nxt; nxt = t;
        }
    }
}

// Round 6
// 243.953 us; speedup vs baseline: 1.3278x; 1.3278x over previous
//
#include <hip/hip_runtime.h>
#include <hip/hip_fp16.h>

#define NUSERS 100000
#define NITEMS 50000
#define NTOT   150000   // NUSERS + NITEMS
#define DIM    64
#define NNZ    2000000
#define NLAYERS 3
#define NB     293      // buckets of 512 rows: 293*512 = 150016 >= NTOT
#define BSH    9        // bucket shift (512 rows)
#define BMSK   511
#define CHUNK  4096     // edges per partition block

typedef _Float16 half2_t __attribute__((ext_vector_type(2)));

// ---------------------------------------------------------------------------
// block-wide inclusive scan, 512 threads: per-wave shfl scan + 8-entry
// cross-wave scan.
// ---------------------------------------------------------------------------
__device__ __forceinline__ int block_incl_scan512(int own, int* wsum, int t) {
    int incl = own;
    #pragma unroll
    for (int o = 1; o < 64; o <<= 1) {
        int v = __shfl_up(incl, o, 64);
        if ((t & 63) >= o) incl += v;
    }
    if ((t & 63) == 63) wsum[t >> 6] = incl;
    __syncthreads();
    if (t < 8) {
        int v = wsum[t];
        #pragma unroll
        for (int o = 1; o < 8; o <<= 1) {
            int u = __shfl_up(v, o, 64);
            if (t >= o) v += u;
        }
        wsum[t] = v;
    }
    __syncthreads();
    if (t >= 64) incl += wsum[(t >> 6) - 1];
    return incl;
}

// ---------------------------------------------------------------------------
// init: b0 = fp16(concat(user_emb, item_emb))   (normal stores — b0 is the
// first gather's table; we WANT it cached)
// ---------------------------------------------------------------------------
__global__ void lg_inith(const float* __restrict__ ue, const float* __restrict__ ie,
                         __half* __restrict__ b0) {
    const int total4 = NTOT * DIM / 4;
    const int ubound4 = NUSERS * DIM / 4;
    const float4* ue4 = (const float4*)ue;
    const float4* ie4 = (const float4*)ie;
    uint2* out = (uint2*)b0;
    for (int i = blockIdx.x * blockDim.x + threadIdx.x; i < total4;
         i += gridDim.x * blockDim.x) {
        const float4 v = (i < ubound4) ? ue4[i] : ie4[i - ubound4];
        __half2 h0 = __floats2half2_rn(v.x, v.y);
        __half2 h1 = __floats2half2_rn(v.z, v.w);
        uint2 u;
        u.x = *(const unsigned int*)&h0;
        u.y = *(const unsigned int*)&h1;
        out[i] = u;
    }
}

// ---------------------------------------------------------------------------
// bucket histogram: bucket = row >> 9. LDS hist, one global atomic/(blk,bkt).
// ---------------------------------------------------------------------------
__global__ void lg_bhist(const int* __restrict__ row, int* __restrict__ bcnt) {
    __shared__ int h[NB];
    for (int i = threadIdx.x; i < NB; i += blockDim.x) h[i] = 0;
    __syncthreads();
    for (int e = blockIdx.x * blockDim.x + threadIdx.x; e < NNZ;
         e += gridDim.x * blockDim.x)
        atomicAdd(&h[row[e] >> BSH], 1);
    __syncthreads();
    for (int i = threadIdx.x; i < NB; i += blockDim.x)
        if (h[i]) atomicAdd(&bcnt[i], h[i]);
}

// ---------------------------------------------------------------------------
// bucket scan: bptr[0..NB] exclusive ptr, bcur = segment cursor base
// ---------------------------------------------------------------------------
__global__ __launch_bounds__(512) void lg_bscan(const int* __restrict__ bcnt,
                                                int* __restrict__ bptr,
                                                int* __restrict__ bcur) {
    __shared__ int wsum[8];
    const int t = threadIdx.x;
    const int own = (t < NB) ? bcnt[t] : 0;
    const int incl = block_incl_scan512(own, wsum, t);
    if (t < NB) {
        bptr[t + 1] = incl;
        bcur[t] = incl - own;
    }
    if (t == 0) bptr[0] = 0;
}

// ---------------------------------------------------------------------------
// partition: chunk-aggregated scatter into bucket segments. LDS-stage CHUNK
// edges grouped by bucket, claim each bucket run with ONE global atomic,
// flush coalesced (normal stores — tmp is read by rsort right after).
// ---------------------------------------------------------------------------
__global__ __launch_bounds__(512) void lg_part(const int* __restrict__ row,
                                               const int* __restrict__ col,
                                               const float* __restrict__ vals,
                                               int* __restrict__ bcur,
                                               int2* __restrict__ tmp) {
    __shared__ int h[NB], off[NB], cnt2[NB], bs[NB];
    __shared__ int wsum[8];
    __shared__ unsigned short bk[CHUNK];
    __shared__ int2 stag[CHUNK];
    const int t = threadIdx.x;
    const int e0 = blockIdx.x * CHUNK;
    const int n = (NNZ - e0 < CHUNK) ? (NNZ - e0) : CHUNK;

    for (int i = t; i < NB; i += 512) { h[i] = 0; cnt2[i] = 0; }
    __syncthreads();
    for (int i = t; i < n; i += 512)
        atomicAdd(&h[row[e0 + i] >> BSH], 1);
    __syncthreads();
    const int own = (t < NB) ? h[t] : 0;
    const int incl = block_incl_scan512(own, wsum, t);
    if (t < NB) off[t] = incl - own;
    __syncthreads();
    for (int i = t; i < n; i += 512) {
        const int e = e0 + i;
        const int r = row[e];
        const int b = r >> BSH;
        const int k = atomicAdd(&cnt2[b], 1);
        const int s = off[b] + k;
        stag[s] = make_int2(((r & BMSK) << 18) | col[e], __float_as_int(vals[e]));
        bk[s] = (unsigned short)b;
    }
    __syncthreads();
    if (t < NB && own > 0) bs[t] = atomicAdd(&bcur[t], own);
    __syncthreads();
    for (int s = t; s < n; s += 512) {
        const int b = bk[s];
        tmp[bs[b] + (s - off[b])] = stag[s];
    }
}

// ---------------------------------------------------------------------------
// rowsort: one block per 512-row bucket. LDS row-hist + two-level scan ->
// per-row [beg,end) in be[]; scatter (col,val) into the bucket's contiguous
// (~55 KB, L2-absorbed) cedge region. NORMAL stores — cedge is reused by all
// three gather dispatches; NT here cost 8x write amplification in round 5.
// ---------------------------------------------------------------------------
__global__ __launch_bounds__(512) void lg_rsort(const int2* __restrict__ tmp,
                                                const int* __restrict__ bptr,
                                                int2* __restrict__ be,
                                                int2* __restrict__ cedge) {
    __shared__ int h[512];
    __shared__ int wsum[8];
    const int b = blockIdx.x;
    const int t = threadIdx.x;
    const int s0 = bptr[b], s1 = bptr[b + 1];
    h[t] = 0;
    __syncthreads();
    for (int s = s0 + t; s < s1; s += 512)
        atomicAdd(&h[(tmp[s].x >> 18) & BMSK], 1);
    __syncthreads();
    const int own = h[t];
    const int incl = block_incl_scan512(own, wsum, t);
    const int excl = incl - own;
    const int r = (b << BSH) + t;
    if (r < NTOT) be[r] = make_int2(s0 + excl, s0 + excl + own);
    __syncthreads();
    h[t] = excl;                        // reuse as per-row cursor
    __syncthreads();
    for (int s = s0 + t; s < s1; s += 512) {
        const int2 ev = tmp[s];
        const int rl = (ev.x >> 18) & BMSK;
        const int k = atomicAdd(&h[rl], 1);
        cedge[s0 + k] = make_int2(ev.x & 0x3FFFF, ev.y);
    }
}

// ---------------------------------------------------------------------------
// gather core: wave = one row. 8 groups x 8 lanes; 2-deep software pipeline;
// inner product via v_dot2_f32_f16 (fdot2) — 4 instructions per 16B instead
// of 12 (cvt+fma). fp32 accumulation.
// ---------------------------------------------------------------------------
__device__ __forceinline__ void acc8(float sum[8], const uint4& q, float v) {
#if __has_builtin(__builtin_amdgcn_fdot2)
    const _Float16 hv = (_Float16)v;
    const half2_t vv = {hv, hv};
    const half2_t* hp = (const half2_t*)&q;
    #pragma unroll
    for (int k = 0; k < 4; ++k)
        sum[2 * k] = __builtin_amdgcn_fdot2(hp[k], vv, sum[2 * k], false);
    // fdot2 merges pairs: sum[2k] holds both elements' contribution.
    // Keep sum[2k+1] = 0; the shfl reduction and writeback handle pairs.
#else
    const __half2* hp = (const __half2*)&q;
    #pragma unroll
    for (int k = 0; k < 4; ++k) {
        const float2 f = __half22float2(hp[k]);
        sum[2 * k]     += v * f.x;
        sum[2 * k + 1] += v * f.y;
    }
#endif
}

// NOTE: fdot2 collapses each half2 pair into ONE float. That changes the
// output layout (4 values/lane, not 8). To keep the epilogue simple and
// identical in both paths, we do NOT use the pair-collapsing form; instead
// use fdot2 with a selector trick: dot((a.x,a.y),(v,0)) = a.x*v and
// dot((a.x,a.y),(0,v)) = a.y*v — one fdot2 per output element (8 per 16B,
// still fewer ops than cvt+2fma = 12, and no layout change).
__device__ __forceinline__ void acc8_safe(float sum[8], const uint4& q, float v) {
#if __has_builtin(__builtin_amdgcn_fdot2)
    const _Float16 hv = (_Float16)v;
    const _Float16 z  = (_Float16)0.0f;
    const half2_t vlo = {hv, z};
    const half2_t vhi = {z, hv};
    const half2_t* hp = (const half2_t*)&q;
    #pragma unroll
    for (int k = 0; k < 4; ++k) {
        sum[2 * k]     = __builtin_amdgcn_fdot2(hp[k], vlo, sum[2 * k], false);
        sum[2 * k + 1] = __builtin_amdgcn_fdot2(hp[k], vhi, sum[2 * k + 1], false);
    }
#else
    const __half2* hp = (const __half2*)&q;
    #pragma unroll
    for (int k = 0; k < 4; ++k) {
        const float2 f = __half22float2(hp[k]);
        sum[2 * k]     += v * f.x;
        sum[2 * k + 1] += v * f.y;
    }
#endif
}

__device__ __forceinline__ void row_gather8(const int2* __restrict__ be,
                                            const int2* __restrict__ cedge,
                                            const __half* __restrict__ cur,
                                            int r, int lane, float sum[8]) {
    const int2 p = be[r];
    const int g = lane >> 3;
    const int d = lane & 7;
    #pragma unroll
    for (int k = 0; k < 8; ++k) sum[k] = 0.0f;
    int e = p.x + g;
    if (e < p.y) {
        long long raw = *(const long long*)&cedge[e];
        uint4 q = ((const uint4*)(cur + ((size_t)(int)raw << 6)))[d];
        for (e += 8; e < p.y; e += 8) {
            const long long raw2 = *(const long long*)&cedge[e];
            const uint4 q2 = ((const uint4*)(cur + ((size_t)(int)raw2 << 6)))[d];
            acc8_safe(sum, q, __int_as_float((int)(raw >> 32)));
            raw = raw2; q = q2;
        }
        acc8_safe(sum, q, __int_as_float((int)(raw >> 32)));
    }
    #pragma unroll
    for (int m = 8; m < 64; m <<= 1) {
        #pragma unroll
        for (int k = 0; k < 8; ++k)
            sum[k] += __shfl_xor(sum[k], m, 64);
    }
}

// mid layer: nxt = fp16(A * cur)   (normal store — nxt is next layer's table)
__global__ void lg_gmid(const int2* __restrict__ be, const int2* __restrict__ cedge,
                        const __half* __restrict__ cur, __half* __restrict__ nxt) {
    const int gid = blockIdx.x * blockDim.x + threadIdx.x;
    const int r = gid >> 6, lane = gid & 63;
    if (r >= NTOT) return;
    float s[8];
    row_gather8(be, cedge, cur, r, lane, s);
    if ((lane >> 3) == 0) {
        __half2 o[4];
        #pragma unroll
        for (int k = 0; k < 4; ++k) o[k] = __floats2half2_rn(s[2 * k], s[2 * k + 1]);
        ((uint4*)(nxt + ((size_t)r << 6)))[lane & 7] = *(const uint4*)o;
    }
}

// last layer, fused: acc = 0.25*(b0 + b1 + b2 + A*b2)   (fp32 output)
__global__ void lg_glast(const int2* __restrict__ be, const int2* __restrict__ cedge,
                         const __half* __restrict__ b0, const __half* __restrict__ b1,
                         const __half* __restrict__ b2, float* __restrict__ acc) {
    const int gid = blockIdx.x * blockDim.x + threadIdx.x;
    const int r = gid >> 6, lane = gid & 63;
    if (r >= NTOT) return;
    float s[8];
    row_gather8(be, cedge, b2, r, lane, s);
    if ((lane >> 3) == 0) {
        const int d = lane & 7;
        const size_t base = (size_t)r << 6;
        const uint4 q0 = ((const uint4*)(b0 + base))[d];
        const uint4 q1 = ((const uint4*)(b1 + base))[d];
        const uint4 q2 = ((const uint4*)(b2 + base))[d];
        const __half2* h0 = (const __half2*)&q0;
        const __half2* h1 = (const __half2*)&q1;
        const __half2* h2 = (const __half2*)&q2;
        float out[8];
        #pragma unroll
        for (int k = 0; k < 4; ++k) {
            const float2 f0 = __half22float2(h0[k]);
            const float2 f1 = __half22float2(h1[k]);
            const float2 f2 = __half22float2(h2[k]);
            out[2 * k]     = 0.25f * (f0.x + f1.x + f2.x + s[2 * k]);
            out[2 * k + 1] = 0.25f * (f0.y + f1.y + f2.y + s[2 * k + 1]);
        }
        float4* dst = (float4*)(acc + base + (size_t)d * 8);
        dst[0] = make_float4(out[0], out[1], out[2], out[3]);
        dst[1] = make_float4(out[4], out[5], out[6], out[7]);
    }
}

// ---------------------------------------------------------------------------
// Fallback (round-1) kernels: edge-parallel scatter with fp32 atomics
// ---------------------------------------------------------------------------
__global__ void lg_init2(const float* __restrict__ ue, const float* __restrict__ ie,
                         float* __restrict__ cur, float* __restrict__ acc) {
    const int total4 = NTOT * DIM / 4;
    const int ubound4 = NUSERS * DIM / 4;
    const float4* ue4 = (const float4*)ue;
    const float4* ie4 = (const float4*)ie;
    float4* cur4 = (float4*)cur;
    float4* acc4 = (float4*)acc;
    for (int i = blockIdx.x * blockDim.x + threadIdx.x; i < total4;
         i += gridDim.x * blockDim.x) {
        float4 v = (i < ubound4) ? ue4[i] : ie4[i - ubound4];
        cur4[i] = v;
        float4 a;
        a.x = 0.25f * v.x; a.y = 0.25f * v.y; a.z = 0.25f * v.z; a.w = 0.25f * v.w;
        acc4[i] = a;
    }
}

__global__ void lg_scatter(const float* __restrict__ cur, const float* __restrict__ vals,
                           const int* __restrict__ row, const int* __restrict__ col,
                           float* __restrict__ next) {
    const long long total = (long long)NNZ * 64;
    for (long long t = blockIdx.x * (long long)blockDim.x + threadIdx.x; t < total;
         t += (long long)gridDim.x * blockDim.x) {
        const int e    = (int)(t >> 6);
        const int lane = (int)(t & 63);
        const float m  = cur[(long long)col[e] * DIM + lane] * vals[e];
        atomicAdd(&next[(long long)row[e] * DIM + lane], m);
    }
}

__global__ void lg_axpy(const float* __restrict__ next, float* __restrict__ acc) {
    const int total4 = NTOT * DIM / 4;
    const float4* n4 = (const float4*)next;
    float4* a4 = (float4*)acc;
    for (int i = blockIdx.x * blockDim.x + threadIdx.x; i < total4;
         i += gridDim.x * blockDim.x) {
        float4 n = n4[i];
        float4 a = a4[i];
        a.x += 0.25f * n.x; a.y += 0.25f * n.y; a.z += 0.25f * n.z; a.w += 0.25f * n.w;
        a4[i] = a;
    }
}

extern "C" void kernel_launch(void* const* d_in, const int* in_sizes, int n_in,
                              void* d_out, int out_size, void* d_ws, size_t ws_size,
                              hipStream_t stream) {
    const float* ue   = (const float*)d_in[0];
    const float* ie   = (const float*)d_in[1];
    const float* vals = (const float*)d_in[2];
    const int*   row  = (const int*)d_in[3];
    const int*   col  = (const int*)d_in[4];

    float* acc = (float*)d_out;

    const size_t EMB = (size_t)NTOT * DIM;       // 9.6M elements

    // workspace layout (fp16 path)
    __half* b0   = (__half*)d_ws;                // 19.2 MB
    __half* b1   = b0 + EMB;                     // 19.2 MB
    __half* b2   = b1 + EMB;                     // 19.2 MB
    int2* tmp    = (int2*)(b2 + EMB);            // 16 MB  (bucket-partitioned)
    int2* cedge  = tmp + NNZ;                    // 16 MB  (row-sorted (col,val))
    int2* be     = cedge + NNZ;                  // 1.2 MB (per-row [beg,end))
    int*  bcnt   = (int*)(be + NTOT);            // NB
    int*  bptr   = bcnt + NB;                    // NB+1
    int*  bcur   = bptr + NB + 1;                // NB
    const size_t need = (size_t)((char*)(bcur + NB) - (char*)d_ws);   // ~90.8 MB

    if (ws_size >= need) {
        const int nchunks = (NNZ + CHUNK - 1) / CHUNK;   // 489
        const int gblocks = (NTOT * DIM) / 256;          // 37500

        lg_inith<<<1024, 256, 0, stream>>>(ue, ie, b0);
        hipMemsetAsync(bcnt, 0, NB * sizeof(int), stream);
        lg_bhist<<<256, 256, 0, stream>>>(row, bcnt);
        lg_bscan<<<1, 512, 0, stream>>>(bcnt, bptr, bcur);
        lg_part<<<nchunks, 512, 0, stream>>>(row, col, vals, bcur, tmp);
        lg_rsort<<<NB, 512, 0, stream>>>(tmp, bptr, be, cedge);

        lg_gmid <<<gblocks, 256, 0, stream>>>(be, cedge, b0, b1);
        lg_gmid <<<gblocks, 256, 0, stream>>>(be, cedge, b1, b2);
        lg_glast<<<gblocks, 256, 0, stream>>>(be, cedge, b0, b1, b2, acc);
    } else {
        // minimal fallback: round-1 scatter path (2 x 38.4 MB fp32)
        float* cur = (float*)d_ws;
        float* nxt = cur + EMB;
        const size_t buf_bytes = EMB * sizeof(float);
        lg_init2<<<1024, 256, 0, stream>>>(ue, ie, cur, acc);
        for (int l = 0; l < NLAYERS; ++l) {
            hipMemsetAsync(nxt, 0, buf_bytes, stream);
            lg_scatter<<<8192, 256, 0, stream>>>(cur, vals, row, col, nxt);
            lg_axpy<<<1024, 256, 0, stream>>>(nxt, acc);
            float* t = cur; cur = nxt; nxt = t;
        }
    }
}

// Round 7
// 238.336 us; speedup vs baseline: 1.3591x; 1.0236x over previous
//
#include <hip/hip_runtime.h>
#include <hip/hip_fp16.h>

#define NUSERS 100000
#define NITEMS 50000
#define NTOT   150000   // NUSERS + NITEMS
#define DIM    64
#define NNZ    2000000
#define NLAYERS 3
#define NB     293      // buckets of 512 rows: 293*512 = 150016 >= NTOT
#define BSH    9        // bucket shift (512 rows)
#define BMSK   511
#define CAP    8192     // fixed bucket capacity (mean 6827, sigma 82.5 -> 16.5 sigma)
#define NSLOTS (NB * 512)
#define CHUNK  4096     // edges per partition block

typedef _Float16 half2_t __attribute__((ext_vector_type(2)));

__device__ __forceinline__ half2_t u2h(unsigned u) {
    union { unsigned u; half2_t h; } c; c.u = u; return c.h;
}

// ---------------------------------------------------------------------------
// block-wide inclusive scan, 512 threads
// ---------------------------------------------------------------------------
__device__ __forceinline__ int block_incl_scan512(int own, int* wsum, int t) {
    int incl = own;
    #pragma unroll
    for (int o = 1; o < 64; o <<= 1) {
        int v = __shfl_up(incl, o, 64);
        if ((t & 63) >= o) incl += v;
    }
    if ((t & 63) == 63) wsum[t >> 6] = incl;
    __syncthreads();
    if (t < 8) {
        int v = wsum[t];
        #pragma unroll
        for (int o = 1; o < 8; o <<= 1) {
            int u = __shfl_up(v, o, 64);
            if (t >= o) v += u;
        }
        wsum[t] = v;
    }
    __syncthreads();
    if (t >= 64) incl += wsum[(t >> 6) - 1];
    return incl;
}

// ---------------------------------------------------------------------------
// init: b0 = fp16(concat(user_emb, item_emb))
// ---------------------------------------------------------------------------
__global__ void lg_inith(const float* __restrict__ ue, const float* __restrict__ ie,
                         __half* __restrict__ b0) {
    const int total4 = NTOT * DIM / 4;
    const int ubound4 = NUSERS * DIM / 4;
    const float4* ue4 = (const float4*)ue;
    const float4* ie4 = (const float4*)ie;
    uint2* out = (uint2*)b0;
    for (int i = blockIdx.x * blockDim.x + threadIdx.x; i < total4;
         i += gridDim.x * blockDim.x) {
        const float4 v = (i < ubound4) ? ue4[i] : ie4[i - ubound4];
        __half2 h0 = __floats2half2_rn(v.x, v.y);
        __half2 h1 = __floats2half2_rn(v.z, v.w);
        uint2 u;
        u.x = *(const unsigned int*)&h0;
        u.y = *(const unsigned int*)&h1;
        out[i] = u;
    }
}

// bcur[b] = b*CAP (fixed-capacity bucket segments; replaces bhist+bscan)
__global__ void lg_binit(int* __restrict__ bcur) {
    const int t = blockIdx.x * blockDim.x + threadIdx.x;
    if (t < NB) bcur[t] = t * CAP;
}

// ---------------------------------------------------------------------------
// partition: chunk-aggregated scatter into fixed-capacity bucket segments.
// LDS-stage CHUNK edges grouped by bucket, claim each bucket run with ONE
// global atomic, flush coalesced. tmp entry: ((row&511)<<18 | col, val_f32).
// ---------------------------------------------------------------------------
__global__ __launch_bounds__(512) void lg_part(const int* __restrict__ row,
                                               const int* __restrict__ col,
                                               const float* __restrict__ vals,
                                               int* __restrict__ bcur,
                                               int2* __restrict__ tmp) {
    __shared__ int h[NB], off[NB], cnt2[NB], bs[NB];
    __shared__ int wsum[8];
    __shared__ unsigned short bk[CHUNK];
    __shared__ int2 stag[CHUNK];
    const int t = threadIdx.x;
    const int e0 = blockIdx.x * CHUNK;
    const int n = (NNZ - e0 < CHUNK) ? (NNZ - e0) : CHUNK;

    for (int i = t; i < NB; i += 512) { h[i] = 0; cnt2[i] = 0; }
    __syncthreads();
    for (int i = t; i < n; i += 512)
        atomicAdd(&h[row[e0 + i] >> BSH], 1);
    __syncthreads();
    const int own = (t < NB) ? h[t] : 0;
    const int incl = block_incl_scan512(own, wsum, t);
    if (t < NB) off[t] = incl - own;
    __syncthreads();
    for (int i = t; i < n; i += 512) {
        const int e = e0 + i;
        const int r = row[e];
        const int b = r >> BSH;
        const int k = atomicAdd(&cnt2[b], 1);
        const int s = off[b] + k;
        stag[s] = make_int2(((r & BMSK) << 18) | col[e], __float_as_int(vals[e]));
        bk[s] = (unsigned short)b;
    }
    __syncthreads();
    if (t < NB && own > 0) bs[t] = atomicAdd(&bcur[t], own);
    __syncthreads();
    for (int s = t; s < n; s += 512) {
        const int b = bk[s];
        tmp[bs[b] + (s - off[b])] = stag[s];
    }
}

// ---------------------------------------------------------------------------
// rowsort: one block per 512-row bucket.
//  - LDS row-hist + scan -> per-row [beg,end) within the bucket's cedge region
//  - LDS counting sort by degree (bins 0..63) -> slot order; waves get
//    near-equal-degree rows (lane-idle from max-deg sync ~0)
//  - scatter edges into cedge as (col<<7 [byte offset], fp16(val) bits)
// sbe[slot]=(beg,end), srid[slot]=row id (-1 for ghost rows >= NTOT)
// ---------------------------------------------------------------------------
__global__ __launch_bounds__(512) void lg_rsort(const int2* __restrict__ tmp,
                                                const int* __restrict__ bcur,
                                                int2* __restrict__ sbe,
                                                int* __restrict__ srid,
                                                int2* __restrict__ cedge) {
    __shared__ int h[512];
    __shared__ int wsum[8];
    __shared__ int dh[64], dcur[64];
    const int b = blockIdx.x;
    const int t = threadIdx.x;
    const int s0 = b * CAP;
    const int s1 = bcur[b];                    // s0 + bucket count (post-part)
    h[t] = 0;
    if (t < 64) dh[t] = 0;
    __syncthreads();
    for (int s = s0 + t; s < s1; s += 512)
        atomicAdd(&h[(tmp[s].x >> 18) & BMSK], 1);
    __syncthreads();
    const int own = h[t];
    const int incl = block_incl_scan512(own, wsum, t);
    const int excl = incl - own;
    const int beg = s0 + excl;
    // degree counting sort
    const int bin = own < 63 ? own : 63;
    atomicAdd(&dh[bin], 1);
    __syncthreads();
    if (t < 64) {
        int v = dh[t];
        int inc = v;
        #pragma unroll
        for (int o = 1; o < 64; o <<= 1) {
            int u = __shfl_up(inc, o, 64);
            if (t >= o) inc += u;
        }
        dcur[t] = inc - v;                     // exclusive base of bin
    }
    __syncthreads();
    const int rank = atomicAdd(&dcur[bin], 1);
    const int r = (b << BSH) + t;
    const int slot = (b << BSH) + rank;
    sbe[slot] = make_int2(beg, beg + own);
    srid[slot] = (r < NTOT) ? r : -1;
    __syncthreads();
    h[t] = excl;                               // reuse as per-row cursor
    __syncthreads();
    for (int s = s0 + t; s < s1; s += 512) {
        const int2 ev = tmp[s];
        const int rl = (ev.x >> 18) & BMSK;
        const int k = atomicAdd(&h[rl], 1);
        const float v = __int_as_float(ev.y);
        const __half hv = __float2half(v);
        const unsigned short hb = *(const unsigned short*)&hv;
        cedge[s0 + k] = make_int2((ev.x & 0x3FFFF) << 7, (int)(unsigned)hb);
    }
}

// ---------------------------------------------------------------------------
// dot: 8 dims (16B fp16) * val, fp32 accumulate. vh holds fp16(val) in low
// half, 0 in high half; vhi = vh<<16 gives the odd-element selector.
// ---------------------------------------------------------------------------
__device__ __forceinline__ void dot8(float sum[8], const uint4& q, unsigned vh) {
#if __has_builtin(__builtin_amdgcn_fdot2)
    const half2_t vlo = u2h(vh);
    const half2_t vhi = u2h(vh << 16);
    const half2_t* hp = (const half2_t*)&q;
    #pragma unroll
    for (int k = 0; k < 4; ++k) {
        sum[2 * k]     = __builtin_amdgcn_fdot2(hp[k], vlo, sum[2 * k],     false);
        sum[2 * k + 1] = __builtin_amdgcn_fdot2(hp[k], vhi, sum[2 * k + 1], false);
    }
#else
    __half hv; *(unsigned short*)&hv = (unsigned short)(vh & 0xFFFF);
    const float v = __half2float(hv);
    const __half2* hp = (const __half2*)&q;
    #pragma unroll
    for (int k = 0; k < 4; ++k) {
        const float2 f = __half22float2(hp[k]);
        sum[2 * k]     += v * f.x;
        sum[2 * k + 1] += v * f.y;
    }
#endif
}

// ---------------------------------------------------------------------------
// gather core: 8-lane group owns one row; lane d accumulates dims [8d,8d+8)
// sequentially over the row's edges. No cross-lane reduction. nit is the
// wave-max degree (SGPR -> SALU loop). Invalid iters: clamped in-segment
// index, colb/vh masked to 0. 2-deep software pipeline.
// ---------------------------------------------------------------------------
__device__ __forceinline__ void row_gather_s(const int2* __restrict__ cedge,
                                             const char* __restrict__ tb,
                                             int beg, int deg, int nit,
                                             float sum[8]) {
    #pragma unroll
    for (int k = 0; k < 8; ++k) sum[k] = 0.0f;
    if (nit <= 0) return;
    const int2* ce = cedge + beg;
    const int degm1 = deg > 0 ? deg - 1 : 0;
    const int2 c0 = ce[0];
    const bool v0 = 0 < deg;
    unsigned colb = v0 ? (unsigned)c0.x : 0u;
    unsigned vh   = v0 ? (unsigned)c0.y : 0u;
    uint4 q = *(const uint4*)(tb + colb);
    for (int it = 1; it < nit; ++it) {
        const int idx = it < degm1 ? it : degm1;
        const int2 c2 = ce[idx];
        const bool v2 = it < deg;
        const unsigned colb2 = v2 ? (unsigned)c2.x : 0u;
        const unsigned vh2   = v2 ? (unsigned)c2.y : 0u;
        const uint4 q2 = *(const uint4*)(tb + colb2);
        dot8(sum, q, vh);
        q = q2; vh = vh2;
    }
    dot8(sum, q, vh);
}

// mid layer: nxt = fp16(A * cur)
__global__ __launch_bounds__(256) void lg_gmid(const int2* __restrict__ sbe,
                                               const int* __restrict__ srid,
                                               const int2* __restrict__ cedge,
                                               const __half* __restrict__ cur,
                                               __half* __restrict__ nxt) {
    const int gid = blockIdx.x * 256 + threadIdx.x;
    const int slot = ((gid >> 6) << 3) + ((gid & 63) >> 3);
    const int d = gid & 7;
    const int2 pe = sbe[slot];
    const int rid = srid[slot];
    const int deg = pe.y - pe.x;
    const int nit = __shfl(deg, 63, 64);       // wave max (degree-sorted)
    float s[8];
    row_gather_s(cedge, (const char*)cur + d * 16, pe.x, deg, nit, s);
    if (rid >= 0) {
        __half2 o[4];
        #pragma unroll
        for (int k = 0; k < 4; ++k) o[k] = __floats2half2_rn(s[2 * k], s[2 * k + 1]);
        ((uint4*)(nxt + ((size_t)rid << 6)))[d] = *(const uint4*)o;
    }
}

// last layer, fused: acc = 0.25*(b0 + b1 + b2 + A*b2)   (fp32 output)
__global__ __launch_bounds__(256) void lg_glast(const int2* __restrict__ sbe,
                                                const int* __restrict__ srid,
                                                const int2* __restrict__ cedge,
                                                const __half* __restrict__ b0,
                                                const __half* __restrict__ b1,
                                                const __half* __restrict__ b2,
                                                float* __restrict__ acc) {
    const int gid = blockIdx.x * 256 + threadIdx.x;
    const int slot = ((gid >> 6) << 3) + ((gid & 63) >> 3);
    const int d = gid & 7;
    const int2 pe = sbe[slot];
    const int rid = srid[slot];
    const int deg = pe.y - pe.x;
    const int nit = __shfl(deg, 63, 64);
    float s[8];
    row_gather_s(cedge, (const char*)b2 + d * 16, pe.x, deg, nit, s);
    if (rid >= 0) {
        const size_t base = (size_t)rid << 6;
        const uint4 q0 = ((const uint4*)(b0 + base))[d];
        const uint4 q1 = ((const uint4*)(b1 + base))[d];
        const uint4 q2 = ((const uint4*)(b2 + base))[d];
        const __half2* h0 = (const __half2*)&q0;
        const __half2* h1 = (const __half2*)&q1;
        const __half2* h2 = (const __half2*)&q2;
        float out[8];
        #pragma unroll
        for (int k = 0; k < 4; ++k) {
            const float2 f0 = __half22float2(h0[k]);
            const float2 f1 = __half22float2(h1[k]);
            const float2 f2 = __half22float2(h2[k]);
            out[2 * k]     = 0.25f * (f0.x + f1.x + f2.x + s[2 * k]);
            out[2 * k + 1] = 0.25f * (f0.y + f1.y + f2.y + s[2 * k + 1]);
        }
        float* dst = acc + base + (size_t)d * 8;
        *(float4*)(dst)     = make_float4(out[0], out[1], out[2], out[3]);
        *(float4*)(dst + 4) = make_float4(out[4], out[5], out[6], out[7]);
    }
}

// ---------------------------------------------------------------------------
// Fallback (round-1) kernels: edge-parallel scatter with fp32 atomics
// ---------------------------------------------------------------------------
__global__ void lg_init2(const float* __restrict__ ue, const float* __restrict__ ie,
                         float* __restrict__ cur, float* __restrict__ acc) {
    const int total4 = NTOT * DIM / 4;
    const int ubound4 = NUSERS * DIM / 4;
    const float4* ue4 = (const float4*)ue;
    const float4* ie4 = (const float4*)ie;
    float4* cur4 = (float4*)cur;
    float4* acc4 = (float4*)acc;
    for (int i = blockIdx.x * blockDim.x + threadIdx.x; i < total4;
         i += gridDim.x * blockDim.x) {
        float4 v = (i < ubound4) ? ue4[i] : ie4[i - ubound4];
        cur4[i] = v;
        float4 a;
        a.x = 0.25f * v.x; a.y = 0.25f * v.y; a.z = 0.25f * v.z; a.w = 0.25f * v.w;
        acc4[i] = a;
    }
}

__global__ void lg_scatter(const float* __restrict__ cur, const float* __restrict__ vals,
                           const int* __restrict__ row, const int* __restrict__ col,
                           float* __restrict__ next) {
    const long long total = (long long)NNZ * 64;
    for (long long t = blockIdx.x * (long long)blockDim.x + threadIdx.x; t < total;
         t += (long long)gridDim.x * blockDim.x) {
        const int e    = (int)(t >> 6);
        const int lane = (int)(t & 63);
        const float m  = cur[(long long)col[e] * DIM + lane] * vals[e];
        atomicAdd(&next[(long long)row[e] * DIM + lane], m);
    }
}

__global__ void lg_axpy(const float* __restrict__ next, float* __restrict__ acc) {
    const int total4 = NTOT * DIM / 4;
    const float4* n4 = (const float4*)next;
    float4* a4 = (float4*)acc;
    for (int i = blockIdx.x * blockDim.x + threadIdx.x; i < total4;
         i += gridDim.x * blockDim.x) {
        float4 n = n4[i];
        float4 a = a4[i];
        a.x += 0.25f * n.x; a.y += 0.25f * n.y; a.z += 0.25f * n.z; a.w += 0.25f * n.w;
        a4[i] = a;
    }
}

extern "C" void kernel_launch(void* const* d_in, const int* in_sizes, int n_in,
                              void* d_out, int out_size, void* d_ws, size_t ws_size,
                              hipStream_t stream) {
    const float* ue   = (const float*)d_in[0];
    const float* ie   = (const float*)d_in[1];
    const float* vals = (const float*)d_in[2];
    const int*   row  = (const int*)d_in[3];
    const int*   col  = (const int*)d_in[4];

    float* acc = (float*)d_out;

    const size_t EMB = (size_t)NTOT * DIM;       // 9.6M elements

    // workspace layout
    __half* b0   = (__half*)d_ws;                // 19.2 MB
    __half* b1   = b0 + EMB;                     // 19.2 MB
    __half* b2   = b1 + EMB;                     // 19.2 MB
    int2* tmp    = (int2*)(b2 + EMB);            // NB*CAP int2 = 19.2 MB
    int2* cedge  = tmp + (size_t)NB * CAP;       // 19.2 MB
    int2* sbe    = cedge + (size_t)NB * CAP;     // NSLOTS int2 = 1.2 MB
    int*  srid   = (int*)(sbe + NSLOTS);         // 0.6 MB
    int*  bcur   = srid + NSLOTS;                // NB
    const size_t need = (size_t)((char*)(bcur + NB) - (char*)d_ws);   // ~97.8 MB

    if (ws_size >= need) {
        const int nchunks = (NNZ + CHUNK - 1) / CHUNK;   // 489
        const int gblocks = NSLOTS * 8 / 256;            // 4688, exact

        lg_inith<<<1024, 256, 0, stream>>>(ue, ie, b0);
        lg_binit<<<1, 512, 0, stream>>>(bcur);
        lg_part<<<nchunks, 512, 0, stream>>>(row, col, vals, bcur, tmp);
        lg_rsort<<<NB, 512, 0, stream>>>(tmp, bcur, sbe, srid, cedge);

        lg_gmid <<<gblocks, 256, 0, stream>>>(sbe, srid, cedge, b0, b1);
        lg_gmid <<<gblocks, 256, 0, stream>>>(sbe, srid, cedge, b1, b2);
        lg_glast<<<gblocks, 256, 0, stream>>>(sbe, srid, cedge, b0, b1, b2, acc);
    } else {
        // minimal fallback: round-1 scatter path (2 x 38.4 MB fp32)
        float* cur = (float*)d_ws;
        float* nxt = cur + EMB;
        const size_t buf_bytes = EMB * sizeof(float);
        lg_init2<<<1024, 256, 0, stream>>>(ue, ie, cur, acc);
        for (int l = 0; l < NLAYERS; ++l) {
            hipMemsetAsync(nxt, 0, buf_bytes, stream);
            lg_scatter<<<8192, 256, 0, stream>>>(cur, vals, row, col, nxt);
            lg_axpy<<<1024, 256, 0, stream>>>(nxt, acc);
            float* t = cur; cur = nxt; nxt = t;
        }
    }
}